// Round 1
// baseline (3583.813 us; speedup 1.0000x reference)
//
#include <hip/hip_runtime.h>
#include <stdint.h>

// Problem dims
#define T_DIM 512
#define B_DIM 64
#define OBS_DIM 128
#define H_DIM 1024
#define C_DIM 512
#define G_DIM 2048   // 4*C
#define A_DIM 32
#define M_ROWS (T_DIM * B_DIM)  // 32768

#define NWG 16  // workgroups in persistent scan kernel

typedef short s16x8 __attribute__((ext_vector_type(8)));
typedef float f32x4 __attribute__((ext_vector_type(4)));

#define AS1(p) ((const __attribute__((address_space(1))) char*)(p))
#define AS3(p) ((__attribute__((address_space(3))) char*)(uintptr_t)(p))

__device__ __forceinline__ unsigned short f2bf(float f) {
  unsigned u = __float_as_uint(f);
  u = (u + 0x7fffu + ((u >> 16) & 1u)) >> 16;  // RNE
  return (unsigned short)u;
}
__device__ __forceinline__ float bf2f(unsigned short u) {
  return __uint_as_float(((unsigned)u) << 16);
}
__device__ __forceinline__ float sigm(float x) { return 1.f / (1.f + __expf(-x)); }
__device__ __forceinline__ float tanhf_(float x) { return 2.f / (1.f + __expf(-2.f * x)) - 1.f; }

// ---------------- cast f32 -> bf16 (vectorized x4) ----------------
__global__ void __launch_bounds__(256) cast_bf16_k(const float* __restrict__ in,
                                                   unsigned short* __restrict__ out, int n4) {
  int i = blockIdx.x * 256 + threadIdx.x;
  int stride = gridDim.x * 256;
  for (; i < n4; i += stride) {
    float4 v = reinterpret_cast<const float4*>(in)[i];
    ushort4 o;
    o.x = f2bf(v.x); o.y = f2bf(v.y); o.z = f2bf(v.z); o.w = f2bf(v.w);
    reinterpret_cast<ushort4*>(out)[i] = o;
  }
}

// ------------- stage 128x32 bf16 tile (8KB) via global_load_lds -------------
__device__ __forceinline__ void stage2(const char* gbase, int ld_bytes, void* lds, int tid) {
  int wave = tid >> 6;
  #pragma unroll
  for (int i = 0; i < 2; ++i) {
    int tb = i * 4096 + tid * 16;  // tile-linear byte
    __builtin_amdgcn_global_load_lds(
        AS1(gbase + (size_t)(tb >> 6) * ld_bytes + (tb & 63)),
        AS3((char*)lds + i * 4096 + wave * 1024), 16, 0, 0);
  }
}

// ---------------- C = op(A @ B^T + bias), bf16 in/out, m97-style ----------------
// A: [M,K] bf16 row-major, B: [N,K] bf16 row-major, C: [M,N] bf16
template <bool RELU>
__global__ void __launch_bounds__(256) gemm_bt_bias(const unsigned short* __restrict__ A,
                                                    const unsigned short* __restrict__ B,
                                                    const float* __restrict__ bias,
                                                    unsigned short* __restrict__ C,
                                                    int M, int N, int K) {
  __shared__ alignas(16) unsigned short lA[4096];
  __shared__ alignas(16) unsigned short lB[4096];
  const int tid = threadIdx.x;
  const int wave = tid >> 6, lane = tid & 63;
  const int l15 = lane & 15, l4 = lane >> 4;
  const int m0 = blockIdx.x * 128, n0 = blockIdx.y * 128;
  const int rw = (wave >> 1) * 64, cn = (wave & 1) * 64;
  const char* Ab = (const char*)A + (size_t)m0 * (K * 2);
  const char* Bb = (const char*)B + (size_t)n0 * (K * 2);

  f32x4 acc[4][4] = {};
  for (int k0 = 0; k0 < K; k0 += 32) {
    stage2(Ab + k0 * 2, K * 2, lA, tid);
    stage2(Bb + k0 * 2, K * 2, lB, tid);
    asm volatile("s_waitcnt vmcnt(0)" ::: "memory");
    __syncthreads();
    s16x8 af[4], bf[4];
    #pragma unroll
    for (int i = 0; i < 4; ++i) {
      af[i] = *reinterpret_cast<const s16x8*>((const char*)lA + (rw + i * 16 + l15) * 64 + l4 * 16);
      bf[i] = *reinterpret_cast<const s16x8*>((const char*)lB + (cn + i * 16 + l15) * 64 + l4 * 16);
    }
    #pragma unroll
    for (int i = 0; i < 4; ++i)
      #pragma unroll
      for (int j = 0; j < 4; ++j)
        acc[i][j] = __builtin_amdgcn_mfma_f32_16x16x32_bf16(af[i], bf[j], acc[i][j], 0, 0, 0);
    __syncthreads();
  }
  #pragma unroll
  for (int i = 0; i < 4; ++i)
    #pragma unroll
    for (int j = 0; j < 4; ++j)
      #pragma unroll
      for (int r = 0; r < 4; ++r) {
        int row = m0 + rw + i * 16 + l4 * 4 + r;
        int col = n0 + cn + j * 16 + l15;
        float v = acc[i][j][r] + bias[col];
        if (RELU) v = fmaxf(v, 0.f);
        C[(size_t)row * N + col] = f2bf(v);
      }
}

// ---------------- grid barrier (device-scope, monotonic counter) ----------------
__device__ __forceinline__ void gridbar(unsigned* cnt, unsigned& nbar) {
  __syncthreads();  // all waves drain their vmem (compiler emits vmcnt(0) at barrier)
  if (threadIdx.x == 0) {
    __threadfence();  // agent release: wbL2 so remote XCDs see our h writes
    __hip_atomic_fetch_add(cnt, 1u, __ATOMIC_RELEASE, __HIP_MEMORY_SCOPE_AGENT);
    const unsigned target = (++nbar) * NWG;
    while (__hip_atomic_load(cnt, __ATOMIC_ACQUIRE, __HIP_MEMORY_SCOPE_AGENT) < target)
      __builtin_amdgcn_s_sleep(1);
  }
  __syncthreads();
}

// ---------------- persistent LSTM scan ----------------
// WG w owns h/c columns [w*32, w*32+32) and gate cols {512g + w*32 + j}.
// Wave g (0..3) handles gate group g: W_hh rows [512g+32w, +32), all K=512, in registers.
// Abuf: [2][64][512] bf16, XOR-swizzled image (byte_in_row ^= (row&7)<<4).
__global__ void __launch_bounds__(256, 1) lstm_scan(
    const unsigned short* __restrict__ gx,   // [T][B][2048] bf16 (incl b_ih)
    const unsigned short* __restrict__ Whh,  // [2048][512] bf16
    const float* __restrict__ bhh,           // [2048]
    const int* __restrict__ masks,           // [T][B]
    const float* __restrict__ h0, const float* __restrict__ c0,  // [B][512]
    unsigned short* __restrict__ Abuf,       // [2][64*512] bf16 swizzled
    unsigned short* __restrict__ hid,        // [T][B][512] bf16
    float* __restrict__ hT, float* __restrict__ cT,
    unsigned* __restrict__ barcnt) {
  __shared__ alignas(16) unsigned short h_lds[64 * 512];  // 64KB swizzled image
  __shared__ alignas(16) float gates_lds[4][64][33];      // +1 pad: conflict-free
  const int tid = threadIdx.x;
  const int wgi = blockIdx.x;
  const int wave = tid >> 6, lane = tid & 63;
  const int l15 = lane & 15, l4 = lane >> 4;

  // --- persistent B fragments: W_hh rows [wave*512 + wgi*32, +32) x K=512 ---
  s16x8 bfr[2][16];
  {
    const unsigned short* wbase = Whh + (size_t)(wave * 512 + wgi * 32) * 512;
    #pragma unroll
    for (int ni = 0; ni < 2; ++ni)
      #pragma unroll
      for (int ks = 0; ks < 16; ++ks)
        bfr[ni][ks] = *reinterpret_cast<const s16x8*>(wbase + (ni * 16 + l15) * 512 + ks * 32 + l4 * 8);
  }

  // cell-phase ownership: thread -> (b, 8 consecutive j)
  const int b_own = tid >> 2;
  const int j0 = (tid & 3) * 8;
  const int colbase = wgi * 32 + j0;

  float bhh_r[4][8];
  #pragma unroll
  for (int g = 0; g < 4; ++g)
    #pragma unroll
    for (int q = 0; q < 8; ++q) bhh_r[g][q] = bhh[g * 512 + colbase + q];

  float c_state[8];
  #pragma unroll
  for (int q = 0; q < 8; ++q) c_state[q] = c0[b_own * 512 + colbase + q];

  // prologue: Abuf[0] slice = h0 * keep[0] (swizzled image)
  {
    float keep0 = 1.f - (float)masks[b_own];
    s16x8 tmp;
    #pragma unroll
    for (int q = 0; q < 8; ++q) tmp[q] = (short)f2bf(h0[b_own * 512 + colbase + q] * keep0);
    unsigned byteoff = ((unsigned)(colbase * 2)) ^ ((unsigned)((b_own & 7) << 4));
    *reinterpret_cast<s16x8*>(reinterpret_cast<char*>(Abuf) + b_own * 1024 + byteoff) = tmp;
  }

  unsigned nbar = 0;
  gridbar(barcnt, nbar);  // Abuf[0] visible everywhere

  #pragma unroll 1
  for (int t = 0; t < T_DIM; ++t) {
    const char* Acur = reinterpret_cast<const char*>(Abuf) + (t & 1) * (64 * 1024);
    // stage full h (64KB) -> LDS, linear copy of swizzled image
    {
      const char* g = Acur + tid * 16;
      #pragma unroll
      for (int i = 0; i < 16; ++i)
        __builtin_amdgcn_global_load_lds(AS1(g + i * 4096),
                                         AS3((char*)h_lds + i * 4096 + wave * 1024), 16, 0, 0);
    }
    asm volatile("s_waitcnt vmcnt(0)" ::: "memory");
    __syncthreads();

    // gates slice = h @ Whh^T  (wave's 32 cols of gate group `wave`)
    f32x4 acc[4][2] = {};
    #pragma unroll
    for (int ks = 0; ks < 16; ++ks) {
      s16x8 a[4];
      #pragma unroll
      for (int mi = 0; mi < 4; ++mi) {
        int row = mi * 16 + l15;
        unsigned byteoff = ((unsigned)(ks * 64 + l4 * 16)) ^ ((unsigned)((row & 7) << 4));
        a[mi] = *reinterpret_cast<const s16x8*>(reinterpret_cast<const char*>(h_lds) + row * 1024 + byteoff);
      }
      #pragma unroll
      for (int mi = 0; mi < 4; ++mi) {
        acc[mi][0] = __builtin_amdgcn_mfma_f32_16x16x32_bf16(a[mi], bfr[0][ks], acc[mi][0], 0, 0, 0);
        acc[mi][1] = __builtin_amdgcn_mfma_f32_16x16x32_bf16(a[mi], bfr[1][ks], acc[mi][1], 0, 0, 0);
      }
    }
    // exchange gates through LDS
    #pragma unroll
    for (int mi = 0; mi < 4; ++mi)
      #pragma unroll
      for (int ni = 0; ni < 2; ++ni)
        #pragma unroll
        for (int r = 0; r < 4; ++r)
          gates_lds[wave][mi * 16 + l4 * 4 + r][ni * 16 + l15] = acc[mi][ni][r];
    __syncthreads();

    // cell update (f32)
    float keep = 1.f - (float)masks[t * 64 + b_own];
    const unsigned short* gxp = gx + ((size_t)t * 64 + b_own) * 2048 + colbase;
    s16x8 gxv[4];
    #pragma unroll
    for (int g = 0; g < 4; ++g) gxv[g] = *reinterpret_cast<const s16x8*>(gxp + g * 512);

    float hn[8];
    #pragma unroll
    for (int q = 0; q < 8; ++q) {
      float pi = gates_lds[0][b_own][j0 + q] + bf2f((unsigned short)gxv[0][q]) + bhh_r[0][q];
      float pf = gates_lds[1][b_own][j0 + q] + bf2f((unsigned short)gxv[1][q]) + bhh_r[1][q];
      float pg = gates_lds[2][b_own][j0 + q] + bf2f((unsigned short)gxv[2][q]) + bhh_r[2][q];
      float po = gates_lds[3][b_own][j0 + q] + bf2f((unsigned short)gxv[3][q]) + bhh_r[3][q];
      float I = sigm(pi), F = sigm(pf), G = tanhf_(pg), O = sigm(po);
      float c = F * (c_state[q] * keep) + I * G;
      c_state[q] = c;
      hn[q] = O * tanhf_(c);
    }
    // hiddens (bf16, linear) for the head GEMM
    {
      s16x8 hb;
      #pragma unroll
      for (int q = 0; q < 8; ++q) hb[q] = (short)f2bf(hn[q]);
      *reinterpret_cast<s16x8*>(hid + ((size_t)t * 64 + b_own) * 512 + colbase) = hb;
    }
    if (t < T_DIM - 1) {
      // next step's A operand: h_new * keep[t+1], swizzled image
      float keepn = 1.f - (float)masks[(t + 1) * 64 + b_own];
      s16x8 ab;
      #pragma unroll
      for (int q = 0; q < 8; ++q) ab[q] = (short)f2bf(hn[q] * keepn);
      unsigned byteoff = ((unsigned)(colbase * 2)) ^ ((unsigned)((b_own & 7) << 4));
      *reinterpret_cast<s16x8*>(reinterpret_cast<char*>(Abuf) + (((t & 1) ^ 1) * 64 * 1024) +
                                b_own * 1024 + byteoff) = ab;
    } else {
      #pragma unroll
      for (int q = 0; q < 8; ++q) {
        hT[b_own * 512 + colbase + q] = hn[q];
        cT[b_own * 512 + colbase + q] = c_state[q];
      }
    }
    gridbar(barcnt, nbar);
  }
}

// ---------------- head: means = tanh(hid @ Wmean^T + b), plus log_std fill ----------------
__global__ void __launch_bounds__(256) head_gemm(const unsigned short* __restrict__ hid,
                                                 const unsigned short* __restrict__ Wmean,
                                                 const float* __restrict__ bmean,
                                                 const float* __restrict__ logstd,
                                                 float* __restrict__ means_out,
                                                 float* __restrict__ logstd_out) {
  __shared__ alignas(16) unsigned short lA[128 * 32];
  __shared__ alignas(16) unsigned short lB[32 * 512];  // full W_mean, 32KB
  const int tid = threadIdx.x;
  const int wave = tid >> 6, lane = tid & 63;
  const int l15 = lane & 15, l4 = lane >> 4;
  const int m0 = blockIdx.x * 128;

  #pragma unroll
  for (int i = 0; i < 8; ++i)
    __builtin_amdgcn_global_load_lds(AS1((const char*)Wmean + i * 4096 + tid * 16),
                                     AS3((char*)lB + i * 4096 + wave * 1024), 16, 0, 0);

  const char* Ab = (const char*)hid + (size_t)m0 * 1024;
  f32x4 acc[2][2] = {};
  for (int k0 = 0; k0 < 512; k0 += 32) {
    stage2(Ab + k0 * 2, 1024, lA, tid);
    asm volatile("s_waitcnt vmcnt(0)" ::: "memory");
    __syncthreads();
    #pragma unroll
    for (int mi = 0; mi < 2; ++mi) {
      int row = wave * 32 + mi * 16 + l15;
      s16x8 a = *reinterpret_cast<const s16x8*>((const char*)lA + row * 64 + l4 * 16);
      #pragma unroll
      for (int ni = 0; ni < 2; ++ni) {
        s16x8 b = *reinterpret_cast<const s16x8*>((const char*)lB + (ni * 16 + l15) * 1024 + k0 * 2 + l4 * 16);
        acc[mi][ni] = __builtin_amdgcn_mfma_f32_16x16x32_bf16(a, b, acc[mi][ni], 0, 0, 0);
      }
    }
    __syncthreads();
  }
  #pragma unroll
  for (int mi = 0; mi < 2; ++mi)
    #pragma unroll
    for (int ni = 0; ni < 2; ++ni)
      #pragma unroll
      for (int r = 0; r < 4; ++r) {
        int row = m0 + wave * 32 + mi * 16 + l4 * 4 + r;
        int col = ni * 16 + l15;
        means_out[(size_t)row * 32 + col] = tanhf_(acc[mi][ni][r] + bmean[col]);
        logstd_out[(size_t)row * 32 + col] = logstd[col];
      }
}

// ---------------- workspace layout (bytes) ----------------
#define OFF_XSBF   0ull
#define OFF_XPROJ  8388608ull
#define OFF_GX     75497472ull
#define OFF_WINBF  209715200ull
#define OFF_WIHBF  209977344ull
#define OFF_WHHBF  214171648ull
#define OFF_WMEANBF 216268800ull
#define OFF_ABUF   216301568ull
#define OFF_BAR    216432640ull
#define OFF_HID    0ull  // overlays xs_bf + x_proj (dead after K2)

extern "C" void kernel_launch(void* const* d_in, const int* in_sizes, int n_in,
                              void* d_out, int out_size, void* d_ws, size_t ws_size,
                              hipStream_t stream) {
  const float* xs = (const float*)d_in[0];
  const float* h0 = (const float*)d_in[1];
  const float* c0 = (const float*)d_in[2];
  const int* masks = (const int*)d_in[3];
  const float* Win = (const float*)d_in[4];
  const float* bin = (const float*)d_in[5];
  const float* Wih = (const float*)d_in[6];
  const float* bih = (const float*)d_in[7];
  const float* Whh = (const float*)d_in[8];
  const float* bhh = (const float*)d_in[9];
  const float* Wmean = (const float*)d_in[10];
  const float* bmean = (const float*)d_in[11];
  const float* logstd = (const float*)d_in[12];

  char* ws = (char*)d_ws;
  unsigned short* xs_bf = (unsigned short*)(ws + OFF_XSBF);
  unsigned short* xproj = (unsigned short*)(ws + OFF_XPROJ);
  unsigned short* gx = (unsigned short*)(ws + OFF_GX);
  unsigned short* win_bf = (unsigned short*)(ws + OFF_WINBF);
  unsigned short* wih_bf = (unsigned short*)(ws + OFF_WIHBF);
  unsigned short* whh_bf = (unsigned short*)(ws + OFF_WHHBF);
  unsigned short* wmean_bf = (unsigned short*)(ws + OFF_WMEANBF);
  unsigned short* abuf = (unsigned short*)(ws + OFF_ABUF);
  unsigned short* hid = (unsigned short*)(ws + OFF_HID);
  unsigned* barcnt = (unsigned*)(ws + OFF_BAR);

  float* means_out = (float*)d_out;
  float* logstd_out = means_out + (size_t)M_ROWS * A_DIM;       // 1,048,576
  float* hTp = means_out + 2ull * M_ROWS * A_DIM;               // 2,097,152
  float* cTp = hTp + (size_t)B_DIM * C_DIM;

  hipMemsetAsync(barcnt, 0, 256, stream);

  auto gsz = [](int n4) { int g = (n4 + 255) / 256; return g > 4096 ? 4096 : g; };
  cast_bf16_k<<<gsz(1048576), 256, 0, stream>>>(xs, xs_bf, 1048576);
  cast_bf16_k<<<gsz(32768), 256, 0, stream>>>(Win, win_bf, 32768);
  cast_bf16_k<<<gsz(524288), 256, 0, stream>>>(Wih, wih_bf, 524288);
  cast_bf16_k<<<gsz(262144), 256, 0, stream>>>(Whh, whh_bf, 262144);
  cast_bf16_k<<<gsz(4096), 256, 0, stream>>>(Wmean, wmean_bf, 4096);

  gemm_bt_bias<true><<<dim3(M_ROWS / 128, H_DIM / 128), 256, 0, stream>>>(
      xs_bf, win_bf, bin, xproj, M_ROWS, H_DIM, OBS_DIM);
  gemm_bt_bias<false><<<dim3(M_ROWS / 128, G_DIM / 128), 256, 0, stream>>>(
      xproj, wih_bf, bih, gx, M_ROWS, G_DIM, H_DIM);

  lstm_scan<<<NWG, 256, 0, stream>>>(gx, whh_bf, bhh, masks, h0, c0, abuf, hid, hTp, cTp, barcnt);

  head_gemm<<<M_ROWS / 128, 256, 0, stream>>>(hid, wmean_bf, bmean, logstd, means_out, logstd_out);
}

// Round 6
// 3309.014 us; speedup vs baseline: 1.0830x; 1.0830x over previous
//
#include <hip/hip_runtime.h>
#include <stdint.h>

// Problem dims
#define T_DIM 512
#define B_DIM 64
#define OBS_DIM 128
#define H_DIM 1024
#define C_DIM 512
#define G_DIM 2048   // 4*C
#define A_DIM 32
#define M_ROWS (T_DIM * B_DIM)  // 32768

#define NWG 16           // workgroups in persistent scan kernel
#define GXW_STRIDE (T_DIM * 64 * 128)  // per-WG packed gx slice, elements

typedef short s16x8 __attribute__((ext_vector_type(8)));
typedef float f32x4 __attribute__((ext_vector_type(4)));
typedef unsigned long long u64;

#define AS1(p) ((const __attribute__((address_space(1))) char*)(p))
#define AS3(p) ((__attribute__((address_space(3))) char*)(uintptr_t)(p))

__device__ __forceinline__ unsigned short f2bf(float f) {
  unsigned u = __float_as_uint(f);
  u = (u + 0x7fffu + ((u >> 16) & 1u)) >> 16;  // RNE
  return (unsigned short)u;
}
__device__ __forceinline__ float bf2f(unsigned short u) {
  return __uint_as_float(((unsigned)u) << 16);
}
__device__ __forceinline__ float sigm(float x) { return 1.f / (1.f + __expf(-x)); }
__device__ __forceinline__ float tanhf_(float x) { return 2.f / (1.f + __expf(-2.f * x)) - 1.f; }

// ---------------- cast f32 -> bf16 (vectorized x4) ----------------
__global__ void __launch_bounds__(256) cast_bf16_k(const float* __restrict__ in,
                                                   unsigned short* __restrict__ out, int n4) {
  int i = blockIdx.x * 256 + threadIdx.x;
  int stride = gridDim.x * 256;
  for (; i < n4; i += stride) {
    float4 v = reinterpret_cast<const float4*>(in)[i];
    ushort4 o;
    o.x = f2bf(v.x); o.y = f2bf(v.y); o.z = f2bf(v.z); o.w = f2bf(v.w);
    reinterpret_cast<ushort4*>(out)[i] = o;
  }
}

// ------------- stage 128x32 bf16 tile (8KB) via global_load_lds -------------
__device__ __forceinline__ void stage2(const char* gbase, int ld_bytes, void* lds, int tid) {
  int wave = tid >> 6;
  #pragma unroll
  for (int i = 0; i < 2; ++i) {
    int tb = i * 4096 + tid * 16;  // tile-linear byte
    __builtin_amdgcn_global_load_lds(
        AS1(gbase + (size_t)(tb >> 6) * ld_bytes + (tb & 63)),
        AS3((char*)lds + i * 4096 + wave * 1024), 16, 0, 0);
  }
}

// ---------------- C = op(A @ B^T + bias), bf16 in/out, m97-style ----------------
// PACKGX: write output in per-WG packed layout gxp[w][row][g*32+j] for the scan.
template <bool RELU, bool PACKGX>
__global__ void __launch_bounds__(256) gemm_bt_bias(const unsigned short* __restrict__ A,
                                                    const unsigned short* __restrict__ B,
                                                    const float* __restrict__ bias,
                                                    unsigned short* __restrict__ C,
                                                    int M, int N, int K) {
  __shared__ alignas(16) unsigned short lA[4096];
  __shared__ alignas(16) unsigned short lB[4096];
  const int tid = threadIdx.x;
  const int wave = tid >> 6, lane = tid & 63;
  const int l15 = lane & 15, l4 = lane >> 4;
  const int m0 = blockIdx.x * 128, n0 = blockIdx.y * 128;
  const int rw = (wave >> 1) * 64, cn = (wave & 1) * 64;
  const char* Ab = (const char*)A + (size_t)m0 * (K * 2);
  const char* Bb = (const char*)B + (size_t)n0 * (K * 2);

  f32x4 acc[4][4] = {};
  for (int k0 = 0; k0 < K; k0 += 32) {
    stage2(Ab + k0 * 2, K * 2, lA, tid);
    stage2(Bb + k0 * 2, K * 2, lB, tid);
    asm volatile("s_waitcnt vmcnt(0)" ::: "memory");
    __syncthreads();
    s16x8 af[4], bf[4];
    #pragma unroll
    for (int i = 0; i < 4; ++i) {
      af[i] = *reinterpret_cast<const s16x8*>((const char*)lA + (rw + i * 16 + l15) * 64 + l4 * 16);
      bf[i] = *reinterpret_cast<const s16x8*>((const char*)lB + (cn + i * 16 + l15) * 64 + l4 * 16);
    }
    #pragma unroll
    for (int i = 0; i < 4; ++i)
      #pragma unroll
      for (int j = 0; j < 4; ++j)
        acc[i][j] = __builtin_amdgcn_mfma_f32_16x16x32_bf16(af[i], bf[j], acc[i][j], 0, 0, 0);
    __syncthreads();
  }
  #pragma unroll
  for (int i = 0; i < 4; ++i)
    #pragma unroll
    for (int j = 0; j < 4; ++j)
      #pragma unroll
      for (int r = 0; r < 4; ++r) {
        int row = m0 + rw + i * 16 + l4 * 4 + r;
        int col = n0 + cn + j * 16 + l15;
        float v = acc[i][j][r] + bias[col];
        if (RELU) v = fmaxf(v, 0.f);
        size_t dst;
        if (PACKGX) {
          int w = (col >> 5) & 15, g = col >> 9, jj = col & 31;
          dst = (size_t)w * GXW_STRIDE + (size_t)row * 128 + g * 32 + jj;
        } else {
          dst = (size_t)row * N + col;
        }
        C[dst] = f2bf(v);
      }
}

// ------- grid barrier v4b: RMW bounded spin + one acquire-inv per step -------
// Spin reads use atomic fetch_add(0): an RMW always executes at the coherent
// point, so freshness is architecturally guaranteed (same mechanism that makes
// cross-XCD atomicAdd correct). Compiler handles register allocation/waitcnt.
// Bounded guard: a protocol failure becomes a fast failed bench, not a hang.
__device__ __forceinline__ void gridbar(unsigned* cnt, unsigned& nbar) {
  asm volatile("s_waitcnt vmcnt(0)" ::: "memory");  // sc1 data stores complete at IF$
  __syncthreads();
  ++nbar;
  if (threadIdx.x == 0) {
    __hip_atomic_fetch_add(cnt, 1u, __ATOMIC_RELAXED, __HIP_MEMORY_SCOPE_AGENT);
    const unsigned target = nbar * NWG;
    int guard = 16384;  // ~5ms worst case; legit waits are <10us
    while (__hip_atomic_fetch_add(cnt, 0u, __ATOMIC_RELAXED, __HIP_MEMORY_SCOPE_AGENT) < target &&
           --guard > 0)
      __builtin_amdgcn_s_sleep(1);
  }
  __syncthreads();
  __builtin_amdgcn_fence(__ATOMIC_ACQUIRE, "agent");  // one buffer_inv; plain loads fresh
}

// ---------------- persistent LSTM scan ----------------
// WG w owns h/c columns [w*32, w*32+32) and gate cols {512g + w*32 + j}.
// Wave g (0..3) handles gate group g: W_hh rows [512g+32w, +32), K=512, in registers.
// Abuf: [2][64][512] bf16, XOR-swizzled image (byte_in_row ^= (row&7)<<4).
// Abuf writes are sc1 (RELAXED/AGENT atomic stores); reads are plain (post-acquire-fence).
__global__ void __launch_bounds__(256, 1) lstm_scan(
    const unsigned short* __restrict__ gxp,  // packed [16][T][64][128] bf16
    const unsigned short* __restrict__ Whh,  // [2048][512] bf16
    const float* __restrict__ bhh,           // [2048]
    const int* __restrict__ masks,           // [T][B]
    const float* __restrict__ h0, const float* __restrict__ c0,  // [B][512]
    unsigned short* __restrict__ Abuf,       // [2][64*512] bf16 swizzled
    unsigned short* __restrict__ hid,        // [T][B][512] bf16
    float* __restrict__ hT, float* __restrict__ cT,
    unsigned* __restrict__ barcnt) {
  __shared__ alignas(16) unsigned short h_lds[64 * 512];  // 64KB swizzled image
  __shared__ alignas(16) float gates_lds[4][64][33];      // +1 pad: conflict-free
  const int tid = threadIdx.x;
  const int wgi = blockIdx.x;
  const int wave = tid >> 6, lane = tid & 63;
  const int l15 = lane & 15, l4 = lane >> 4;

  // --- persistent B fragments: W_hh rows [wave*512 + wgi*32, +32) x K=512 ---
  s16x8 bfr[2][16];
  {
    const unsigned short* wbase = Whh + (size_t)(wave * 512 + wgi * 32) * 512;
    #pragma unroll
    for (int ni = 0; ni < 2; ++ni)
      #pragma unroll
      for (int ks = 0; ks < 16; ++ks)
        bfr[ni][ks] = *reinterpret_cast<const s16x8*>(wbase + (ni * 16 + l15) * 512 + ks * 32 + l4 * 8);
  }

  // cell-phase ownership: thread -> (b, 8 consecutive j)
  const int b_own = tid >> 2;
  const int j0 = (tid & 3) * 8;
  const int colbase = wgi * 32 + j0;
  const unsigned swz_byteoff = ((unsigned)(colbase * 2)) ^ ((unsigned)((b_own & 7) << 4));
  const unsigned short* gxw = gxp + (size_t)wgi * GXW_STRIDE;

  float bhh_r[4][8];
  #pragma unroll
  for (int g = 0; g < 4; ++g)
    #pragma unroll
    for (int q = 0; q < 8; ++q) bhh_r[g][q] = bhh[g * 512 + colbase + q];

  float c_state[8];
  #pragma unroll
  for (int q = 0; q < 8; ++q) c_state[q] = c0[b_own * 512 + colbase + q];

  // gx / mask prefetch state (packed: 4 x 16B contiguous per thread)
  s16x8 gx_cur[4];
  int m_cur = masks[b_own];
  int m_nxt = masks[64 + b_own];
  {
    const unsigned short* gp = gxw + (size_t)b_own * 128 + j0;
    #pragma unroll
    for (int g = 0; g < 4; ++g) gx_cur[g] = *reinterpret_cast<const s16x8*>(gp + g * 32);
  }

  // prologue: Abuf[0] slice = h0 * keep[0] (swizzled image), via sc1 stores
  {
    float keep0 = 1.f - (float)m_cur;
    u64 lo = 0, hi = 0;
    #pragma unroll
    for (int q = 0; q < 4; ++q) lo |= (u64)f2bf(h0[b_own * 512 + colbase + q] * keep0) << (16 * q);
    #pragma unroll
    for (int q = 0; q < 4; ++q) hi |= (u64)f2bf(h0[b_own * 512 + colbase + 4 + q] * keep0) << (16 * q);
    u64* dst = (u64*)(reinterpret_cast<char*>(Abuf) + b_own * 1024 + swz_byteoff);
    __hip_atomic_store(dst, lo, __ATOMIC_RELAXED, __HIP_MEMORY_SCOPE_AGENT);
    __hip_atomic_store(dst + 1, hi, __ATOMIC_RELAXED, __HIP_MEMORY_SCOPE_AGENT);
  }

  unsigned nbar = 0;
  gridbar(barcnt, nbar);  // Abuf[0] visible everywhere

  #pragma unroll 1
  for (int t = 0; t < T_DIM; ++t) {
    // ---- stage full h (64KB swizzled image) -> LDS via global_load_lds (plain loads)
    {
      const char* g = reinterpret_cast<const char*>(Abuf) + (t & 1) * 65536 + tid * 16;
      #pragma unroll
      for (int i = 0; i < 16; ++i)
        __builtin_amdgcn_global_load_lds(AS1(g + i * 4096),
                                         AS3((char*)h_lds + i * 4096 + wave * 1024), 16, 0, 0);
    }
    asm volatile("s_waitcnt vmcnt(0)" ::: "memory");
    __syncthreads();

    // ---- prefetch next step's gx / mask into registers (hidden under MFMA)
    s16x8 gx_nxt[4];
    int m_fut = 0;
    if (t < T_DIM - 1) {
      const unsigned short* gp = gxw + (size_t)(t + 1) * 8192 + b_own * 128 + j0;
      #pragma unroll
      for (int g = 0; g < 4; ++g) gx_nxt[g] = *reinterpret_cast<const s16x8*>(gp + g * 32);
      if (t + 2 < T_DIM) m_fut = masks[(t + 2) * 64 + b_own];
    }

    // ---- gates slice = h @ Whh^T  (wave's 32 cols of gate group `wave`)
    f32x4 acc[4][2] = {};
    #pragma unroll
    for (int ks = 0; ks < 16; ++ks) {
      s16x8 a[4];
      #pragma unroll
      for (int mi = 0; mi < 4; ++mi) {
        int row = mi * 16 + l15;
        unsigned byteoff = ((unsigned)(ks * 64 + l4 * 16)) ^ ((unsigned)((row & 7) << 4));
        a[mi] = *reinterpret_cast<const s16x8*>(reinterpret_cast<const char*>(h_lds) + row * 1024 + byteoff);
      }
      #pragma unroll
      for (int mi = 0; mi < 4; ++mi) {
        acc[mi][0] = __builtin_amdgcn_mfma_f32_16x16x32_bf16(a[mi], bfr[0][ks], acc[mi][0], 0, 0, 0);
        acc[mi][1] = __builtin_amdgcn_mfma_f32_16x16x32_bf16(a[mi], bfr[1][ks], acc[mi][1], 0, 0, 0);
      }
    }
    // exchange gates through LDS
    #pragma unroll
    for (int mi = 0; mi < 4; ++mi)
      #pragma unroll
      for (int ni = 0; ni < 2; ++ni)
        #pragma unroll
        for (int r = 0; r < 4; ++r)
          gates_lds[wave][mi * 16 + l4 * 4 + r][ni * 16 + l15] = acc[mi][ni][r];
    __syncthreads();

    // ---- cell update (f32)
    float keep = 1.f - (float)m_cur;
    float hn[8];
    #pragma unroll
    for (int q = 0; q < 8; ++q) {
      float pi = gates_lds[0][b_own][j0 + q] + bf2f((unsigned short)gx_cur[0][q]) + bhh_r[0][q];
      float pf = gates_lds[1][b_own][j0 + q] + bf2f((unsigned short)gx_cur[1][q]) + bhh_r[1][q];
      float pg = gates_lds[2][b_own][j0 + q] + bf2f((unsigned short)gx_cur[2][q]) + bhh_r[2][q];
      float po = gates_lds[3][b_own][j0 + q] + bf2f((unsigned short)gx_cur[3][q]) + bhh_r[3][q];
      float I = sigm(pi), F = sigm(pf), G = tanhf_(pg), O = sigm(po);
      float c = F * (c_state[q] * keep) + I * G;
      c_state[q] = c;
      hn[q] = O * tanhf_(c);
    }
    // hiddens (bf16, linear, plain cached store) for the head GEMM
    {
      s16x8 hb;
      #pragma unroll
      for (int q = 0; q < 8; ++q) hb[q] = (short)f2bf(hn[q]);
      *reinterpret_cast<s16x8*>(hid + ((size_t)t * 64 + b_own) * 512 + colbase) = hb;
    }
    if (t < T_DIM - 1) {
      // next step's A operand: h_new * keep[t+1] -> Abuf other half (swizzled), sc1
      float keepn = 1.f - (float)m_nxt;
      u64 lo = 0, hi = 0;
      #pragma unroll
      for (int q = 0; q < 4; ++q) lo |= (u64)f2bf(hn[q] * keepn) << (16 * q);
      #pragma unroll
      for (int q = 0; q < 4; ++q) hi |= (u64)f2bf(hn[4 + q] * keepn) << (16 * q);
      u64* dst = (u64*)(reinterpret_cast<char*>(Abuf) + (((t & 1) ^ 1) * 65536) +
                        b_own * 1024 + swz_byteoff);
      __hip_atomic_store(dst, lo, __ATOMIC_RELAXED, __HIP_MEMORY_SCOPE_AGENT);
      __hip_atomic_store(dst + 1, hi, __ATOMIC_RELAXED, __HIP_MEMORY_SCOPE_AGENT);
      #pragma unroll
      for (int g = 0; g < 4; ++g) gx_cur[g] = gx_nxt[g];
      m_cur = m_nxt;
      m_nxt = m_fut;
      gridbar(barcnt, nbar);
    } else {
      #pragma unroll
      for (int q = 0; q < 8; ++q) {
        hT[b_own * 512 + colbase + q] = hn[q];
        cT[b_own * 512 + colbase + q] = c_state[q];
      }
      // no final barrier needed: kernel end flushes everything
    }
  }
}

// ---------------- head: means = tanh(hid @ Wmean^T + b), plus log_std fill ----------------
__global__ void __launch_bounds__(256) head_gemm(const unsigned short* __restrict__ hid,
                                                 const unsigned short* __restrict__ Wmean,
                                                 const float* __restrict__ bmean,
                                                 const float* __restrict__ logstd,
                                                 float* __restrict__ means_out,
                                                 float* __restrict__ logstd_out) {
  __shared__ alignas(16) unsigned short lA[128 * 32];
  __shared__ alignas(16) unsigned short lB[32 * 512];  // full W_mean, 32KB
  const int tid = threadIdx.x;
  const int wave = tid >> 6, lane = tid & 63;
  const int l15 = lane & 15, l4 = lane >> 4;
  const int m0 = blockIdx.x * 128;

  #pragma unroll
  for (int i = 0; i < 8; ++i)
    __builtin_amdgcn_global_load_lds(AS1((const char*)Wmean + i * 4096 + tid * 16),
                                     AS3((char*)lB + i * 4096 + wave * 1024), 16, 0, 0);

  const char* Ab = (const char*)hid + (size_t)m0 * 1024;
  f32x4 acc[2][2] = {};
  for (int k0 = 0; k0 < 512; k0 += 32) {
    stage2(Ab + k0 * 2, 1024, lA, tid);
    asm volatile("s_waitcnt vmcnt(0)" ::: "memory");
    __syncthreads();
    #pragma unroll
    for (int mi = 0; mi < 2; ++mi) {
      int row = wave * 32 + mi * 16 + l15;
      s16x8 a = *reinterpret_cast<const s16x8*>((const char*)lA + row * 64 + l4 * 16);
      #pragma unroll
      for (int ni = 0; ni < 2; ++ni) {
        s16x8 b = *reinterpret_cast<const s16x8*>((const char*)lB + (ni * 16 + l15) * 1024 + k0 * 2 + l4 * 16);
        acc[mi][ni] = __builtin_amdgcn_mfma_f32_16x16x32_bf16(a, b, acc[mi][ni], 0, 0, 0);
      }
    }
    __syncthreads();
  }
  #pragma unroll
  for (int mi = 0; mi < 2; ++mi)
    #pragma unroll
    for (int ni = 0; ni < 2; ++ni)
      #pragma unroll
      for (int r = 0; r < 4; ++r) {
        int row = m0 + wave * 32 + mi * 16 + l4 * 4 + r;
        int col = ni * 16 + l15;
        means_out[(size_t)row * 32 + col] = tanhf_(acc[mi][ni][r] + bmean[col]);
        logstd_out[(size_t)row * 32 + col] = logstd[col];
      }
}

// ---------------- workspace layout (bytes) ----------------
#define OFF_XSBF   0ull
#define OFF_XPROJ  8388608ull
#define OFF_GX     75497472ull
#define OFF_WINBF  209715200ull
#define OFF_WIHBF  209977344ull
#define OFF_WHHBF  214171648ull
#define OFF_WMEANBF 216268800ull
#define OFF_ABUF   216301568ull
#define OFF_BAR    216432640ull
#define OFF_HID    0ull  // overlays xs_bf + x_proj (dead after K2)

extern "C" void kernel_launch(void* const* d_in, const int* in_sizes, int n_in,
                              void* d_out, int out_size, void* d_ws, size_t ws_size,
                              hipStream_t stream) {
  const float* xs = (const float*)d_in[0];
  const float* h0 = (const float*)d_in[1];
  const float* c0 = (const float*)d_in[2];
  const int* masks = (const int*)d_in[3];
  const float* Win = (const float*)d_in[4];
  const float* bin = (const float*)d_in[5];
  const float* Wih = (const float*)d_in[6];
  const float* bih = (const float*)d_in[7];
  const float* Whh = (const float*)d_in[8];
  const float* bhh = (const float*)d_in[9];
  const float* Wmean = (const float*)d_in[10];
  const float* bmean = (const float*)d_in[11];
  const float* logstd = (const float*)d_in[12];

  char* ws = (char*)d_ws;
  unsigned short* xs_bf = (unsigned short*)(ws + OFF_XSBF);
  unsigned short* xproj = (unsigned short*)(ws + OFF_XPROJ);
  unsigned short* gx = (unsigned short*)(ws + OFF_GX);
  unsigned short* win_bf = (unsigned short*)(ws + OFF_WINBF);
  unsigned short* wih_bf = (unsigned short*)(ws + OFF_WIHBF);
  unsigned short* whh_bf = (unsigned short*)(ws + OFF_WHHBF);
  unsigned short* wmean_bf = (unsigned short*)(ws + OFF_WMEANBF);
  unsigned short* abuf = (unsigned short*)(ws + OFF_ABUF);
  unsigned short* hid = (unsigned short*)(ws + OFF_HID);
  unsigned* barcnt = (unsigned*)(ws + OFF_BAR);

  float* means_out = (float*)d_out;
  float* logstd_out = means_out + (size_t)M_ROWS * A_DIM;       // 1,048,576
  float* hTp = means_out + 2ull * M_ROWS * A_DIM;               // 2,097,152
  float* cTp = hTp + (size_t)B_DIM * C_DIM;

  hipMemsetAsync(barcnt, 0, 256, stream);

  auto gsz = [](int n4) { int g = (n4 + 255) / 256; return g > 4096 ? 4096 : g; };
  cast_bf16_k<<<gsz(1048576), 256, 0, stream>>>(xs, xs_bf, 1048576);
  cast_bf16_k<<<gsz(32768), 256, 0, stream>>>(Win, win_bf, 32768);
  cast_bf16_k<<<gsz(524288), 256, 0, stream>>>(Wih, wih_bf, 524288);
  cast_bf16_k<<<gsz(262144), 256, 0, stream>>>(Whh, whh_bf, 262144);
  cast_bf16_k<<<gsz(4096), 256, 0, stream>>>(Wmean, wmean_bf, 4096);

  gemm_bt_bias<true, false><<<dim3(M_ROWS / 128, H_DIM / 128), 256, 0, stream>>>(
      xs_bf, win_bf, bin, xproj, M_ROWS, H_DIM, OBS_DIM);
  gemm_bt_bias<false, true><<<dim3(M_ROWS / 128, G_DIM / 128), 256, 0, stream>>>(
      xproj, wih_bf, bih, gx, M_ROWS, G_DIM, H_DIM);

  lstm_scan<<<NWG, 256, 0, stream>>>(gx, whh_bf, bhh, masks, h0, c0, abuf, hid, hTp, cTp, barcnt);

  head_gemm<<<M_ROWS / 128, 256, 0, stream>>>(hid, wmean_bf, bmean, logstd, means_out, logstd_out);
}